// Round 1
// baseline (155.340 us; speedup 1.0000x reference)
//
#include <hip/hip_runtime.h>
#include <hip/hip_bf16.h>
#include <stdint.h>

// out[b,t,o] = bias[o] + sum_{c<7,m<8,h<3} W[o, c*8+m, h] * Z[b, c*8+m, (t+h-1)&2047]
// Z[b, cm, s] = (s >= 168) ? x[b, s-24m, c] : 0
//
// Tap-major fused design: LDS holds G directly in MFMA B-fragment order.
//   gt[qp][lb][j] = bf16( x[b, ttw-24j, qp] ),  ttw = (t0+lb-1)&2047,
//   zeroed when ttw<168 or qp==7 (mask baked in at stage time).
// B-fragment for (h,kc,ni) = one aligned ds_read_b128 at
//   &gt[qp][wt+ni*16+l15+h][0]  (consecutive 16B per lane -> conflict-free).
// A-operand = pre-swizzled Wf (direct global loads, L2-resident).
// C/D regs hold 4 consecutive o -> dwordx4 stores.

#define TAO    24
#define MTAPS  7
#define C_IN   7
#define SEQ    2048
#define DMODEL 512
#define NROWS  65536   // 32*2048
#define BO     128     // o per block
#define BT     128     // t per block
#define GROWS  130     // staged G rows: lbase in [0, 130)
#define GPLANE 1056    // padded plane stride in shorts (132 rows * 8 taps)

typedef __attribute__((ext_vector_type(8))) short frag_ab;  // 8 bf16
typedef __attribute__((ext_vector_type(4))) float frag_cd;  // 4 fp32

// ---------------- prep: fragment-swizzled W only ----------------
// Wf[((h*32+oc)*2+kc)*64 + lane][j] = W[o*168 + k*3 + h],
//   o = oc*16 + (lane&15), k = kc*32 + (lane>>4)*8 + j, zero for k >= 56.
__global__ __launch_bounds__(256)
void prep_w_kernel(const float* __restrict__ W, __hip_bfloat16* __restrict__ Wf)
{
    const int idx  = blockIdx.x * 256 + threadIdx.x;   // [0, 12288)
    const int lane = idx & 63;
    const int kc   = (idx >> 6) & 1;
    const int oc   = (idx >> 7) & 31;
    const int h    = idx >> 12;
    const int o    = oc * 16 + (lane & 15);
    const int kof  = kc * 32 + (lane >> 4) * 8;

    union { __hip_bfloat16 s[8]; int4 v; } u;
#pragma unroll
    for (int j = 0; j < 8; j++) {
        const int k = kof + j;
        float v = (k < 56) ? W[o * 168 + k * 3 + h] : 0.0f;
        u.s[j] = __float2bfloat16(v);
    }
    ((int4*)Wf)[idx] = u.v;
}

// ---------------- fused GEMM ----------------
__global__ __launch_bounds__(256, 3)
void gemm_kernel(const float* __restrict__ x,
                 const __hip_bfloat16* __restrict__ Wf,
                 const float* __restrict__ bias,
                 float* __restrict__ out)
{
    // tap-major G tile: plane qp (=c), row lb (=local t+h), tap j. 16896 B.
    __shared__ __align__(16) short gt[8 * GPLANE];

    const int tid = threadIdx.x;
    const int bo  = blockIdx.x & 3;      // 4 o-blocks
    const int mb  = blockIdx.x >> 2;     // 512 t-blocks
    const int b   = mb >> 4;
    const int t0  = (mb & 15) * BT;
    const int o0  = bo * BO;

    // --- stage G directly from global x, fragment-ordered, mask baked in.
    {
        const float* xb = x + b * (SEQ * C_IN);
#pragma unroll
        for (int it = 0; it < 5; it++) {
            const int idx = it * 256 + tid;          // (qp, lb) pair
            if (idx < 8 * GROWS) {
                const int qp = idx / GROWS;
                const int lb = idx - qp * GROWS;
                const int ttw = (t0 + lb - 1 + SEQ) & (SEQ - 1);
                union { short s[8]; int4 v; } u;
                if ((ttw >= MTAPS * TAO) && (qp < 7)) {
                    const float* p = xb + ttw * C_IN + qp;
#pragma unroll
                    for (int j = 0; j < 8; j++) {
                        __hip_bfloat16 bv = __float2bfloat16(p[-168 * j]); // tap stride 24 rows
                        u.s[j] = *reinterpret_cast<short*>(&bv);
                    }
                } else {
                    u.v = (int4){0, 0, 0, 0};
                }
                *(int4*)&gt[qp * GPLANE + lb * 8] = u.v;
            }
        }
    }

    // --- wave geometry; waves 2(o) x 2(t); wave tile 64 o x 64 t
    const int wave = tid >> 6;
    const int lane = tid & 63;
    const int wo   = (wave >> 1) * 64;
    const int wt   = (wave & 1) * 64;
    const int l15  = lane & 15;
    const int quad = lane >> 4;

    frag_cd acc[4][4];
#pragma unroll
    for (int i = 0; i < 4; i++)
#pragma unroll
        for (int j = 0; j < 4; j++)
            acc[i][j] = (frag_cd){0.f, 0.f, 0.f, 0.f};

    __syncthreads();

    const int octile = bo * 8 + (wo >> 4);   // o-chunk base (units of 16 o)
#pragma unroll
    for (int h = 0; h < 3; h++) {
#pragma unroll
        for (int kc = 0; kc < 2; kc++) {
            const int qp = kc * 4 + quad;            // channel plane
            frag_ab wfr[4];
#pragma unroll
            for (int mi = 0; mi < 4; mi++) {
                const int tile = (h * 32 + octile + mi) * 2 + kc;
                wfr[mi] = *(const frag_ab*)((const char*)Wf + (size_t)tile * 1024 + lane * 16);
            }
            // --- B fragments: one aligned b128 read each, no masking VALU
            const short* gp = &gt[qp * GPLANE + (wt + l15 + h) * 8];
            frag_ab g[4];
#pragma unroll
            for (int ni = 0; ni < 4; ni++)
                g[ni] = *(const frag_ab*)(gp + ni * 128);   // +ni*16 rows = 256B imm
#pragma unroll
            for (int mi = 0; mi < 4; mi++)
#pragma unroll
                for (int ni = 0; ni < 4; ni++)
                    acc[mi][ni] = __builtin_amdgcn_mfma_f32_16x16x32_bf16(
                        wfr[mi], g[ni], acc[mi][ni], 0, 0, 0);
        }
    }

    // --- epilogue: C/D col = lane&15 = t, row = quad*4+reg = o -> dwordx4
    float4 bias4[4];
#pragma unroll
    for (int mi = 0; mi < 4; mi++)
        bias4[mi] = *(const float4*)&bias[o0 + wo + mi * 16 + quad * 4];

    const size_t rowbase = (size_t)b * SEQ + t0 + wt;
#pragma unroll
    for (int ni = 0; ni < 4; ni++) {
        const size_t r = rowbase + ni * 16 + l15;
        float* orow = out + r * DMODEL + o0 + wo + quad * 4;
#pragma unroll
        for (int mi = 0; mi < 4; mi++) {
            float4 v;
            v.x = acc[mi][ni][0] + bias4[mi].x;
            v.y = acc[mi][ni][1] + bias4[mi].y;
            v.z = acc[mi][ni][2] + bias4[mi].z;
            v.w = acc[mi][ni][3] + bias4[mi].w;
            *(float4*)(orow + mi * 16) = v;
        }
    }
}

// ---------------- fallback (round-1, known-correct, no ws) ----------------
#define KDIM  168
#define KPAD  192
#define FLDK  200
__global__ __launch_bounds__(256, 1)
void fused_tokenconv_kernel(const float* __restrict__ x,
                            const float* __restrict__ W,
                            const float* __restrict__ bias,
                            float* __restrict__ out)
{
    __shared__ __hip_bfloat16 As[128][FLDK];
    __shared__ __hip_bfloat16 Bs[128][FLDK];
    const int tid = threadIdx.x;
    const int blk = blockIdx.x;
    const int nb  = blk & 3;
    const int mb  = blk >> 2;
    const int b   = mb >> 4;
    const int t0  = (mb & 15) * 128;
    const int o0  = nb * 128;
    const float* xb = x + b * (SEQ * C_IN);

    for (int idx = tid; idx < 128 * KPAD; idx += 256) {
        int o_l = idx / KPAD;
        int i   = idx - o_l * KPAD;
        float v = (i < KDIM) ? W[(o0 + o_l) * KDIM + i] : 0.0f;
        Bs[o_l][i] = __float2bfloat16(v);
    }
    for (int idx = tid; idx < 128 * KPAD; idx += 256) {
        int t_l = idx / KPAD;
        int i   = idx - t_l * KPAD;
        float v = 0.0f;
        if (i < KDIM) {
            int c = i / 24;
            int r = i - c * 24;
            int m = r / 3;
            int h = r - m * 3;
            int s = (t0 + t_l + h - 1 + SEQ) & (SEQ - 1);
            if (s >= MTAPS * TAO) v = xb[(s - TAO * m) * C_IN + c];
        }
        As[t_l][i] = __float2bfloat16(v);
    }
    __syncthreads();

    const int wave = tid >> 6;
    const int lane = tid & 63;
    const int wm   = (wave >> 1) * 64;
    const int wn   = (wave & 1) * 64;
    const int l15  = lane & 15;
    const int quad = lane >> 4;

    frag_cd acc[4][4];
#pragma unroll
    for (int i = 0; i < 4; i++)
#pragma unroll
        for (int j = 0; j < 4; j++)
            acc[i][j] = (frag_cd){0.f, 0.f, 0.f, 0.f};

#pragma unroll
    for (int kc = 0; kc < KPAD / 32; kc++) {
        const int kof = kc * 32 + quad * 8;
        frag_ab a[4], bf[4];
#pragma unroll
        for (int mi = 0; mi < 4; mi++)
            a[mi] = *(const frag_ab*)&As[wm + mi * 16 + l15][kof];
#pragma unroll
        for (int ni = 0; ni < 4; ni++)
            bf[ni] = *(const frag_ab*)&Bs[wn + ni * 16 + l15][kof];
#pragma unroll
        for (int mi = 0; mi < 4; mi++)
#pragma unroll
            for (int ni = 0; ni < 4; ni++)
                acc[mi][ni] = __builtin_amdgcn_mfma_f32_16x16x32_bf16(
                    a[mi], bf[ni], acc[mi][ni], 0, 0, 0);
    }
    float* outb = out + (size_t)b * SEQ * DMODEL;
#pragma unroll
    for (int ni = 0; ni < 4; ni++) {
        const int o  = o0 + wn + ni * 16 + l15;
        const float bvv = bias[o];
#pragma unroll
        for (int mi = 0; mi < 4; mi++) {
#pragma unroll
            for (int reg = 0; reg < 4; reg++) {
                const int t = t0 + wm + mi * 16 + quad * 4 + reg;
                outb[(size_t)t * DMODEL + o] = acc[mi][ni][reg] + bvv;
            }
        }
    }
}

extern "C" void kernel_launch(void* const* d_in, const int* in_sizes, int n_in,
                              void* d_out, int out_size, void* d_ws, size_t ws_size,
                              hipStream_t stream) {
    const float* x    = (const float*)d_in[0];   // (32, 2048, 7) fp32
    const float* W    = (const float*)d_in[1];   // (512, 56, 3) fp32
    const float* bias = (const float*)d_in[2];   // (512,) fp32
    float* out        = (float*)d_out;           // (32, 2048, 512) fp32

    const size_t w_bytes = (size_t)12288 * 16;   // 196,608
    if (ws_size >= w_bytes) {
        __hip_bfloat16* Wf = (__hip_bfloat16*)d_ws;
        hipLaunchKernelGGL(prep_w_kernel, dim3(48), dim3(256), 0, stream, W, Wf);
        hipLaunchKernelGGL(gemm_kernel, dim3((DMODEL / BO) * (NROWS / BT)), dim3(256), 0, stream,
                           x, Wf, bias, out);
    } else {
        hipLaunchKernelGGL(fused_tokenconv_kernel, dim3(32 * 16 * 4), dim3(256), 0, stream,
                           x, W, bias, out);
    }
}